// Round 6
// baseline (414.341 us; speedup 1.0000x reference)
//
#include <hip/hip_runtime.h>
#include <math.h>

#define BB 16
#define TT 4096
#define DD 1024
#define HH 32
#define GROUPB 4                 // batches per group (4 * 32MB = 128MB <= L3/2)
#define NGROUP (BB / GROUPB)     // 4
#define RCHUNK 16                // t-rows per block
#define NCH (TT / RCHUNK)        // 256 chunks per batch

static constexpr float kEPS = 1e-6f;

typedef float f32x4 __attribute__((ext_vector_type(4)));

// ---------------- K1: masked partial sums for one group of 4 batches --------
// grid: (NCH, GROUPB), 256 threads; thread owns 4 consecutive d.
// Normal loads: this seeds L3 with the group's 128MB for K3's re-read.
__global__ __launch_bounds__(256) void reduce_kernel(
    const float* __restrict__ zr, const float* __restrict__ zi,
    const float* __restrict__ mask,
    float* __restrict__ partR, float* __restrict__ partI,
    float* __restrict__ cntP, int gbase) {
  const int c = blockIdx.x;
  const int gb = blockIdx.y;
  const int b = gbase + gb;
  const int tid = threadIdx.x;
  const int d4 = tid * 4;

  f32x4 accR = (f32x4)(0.f);
  f32x4 accI = (f32x4)(0.f);
  float msum = 0.f;

  const size_t base = ((size_t)b * TT + (size_t)c * RCHUNK) * DD + d4;
  const float* zrp = zr + base;
  const float* zip = zi + base;
  const float* mp = mask + (size_t)b * TT + (size_t)c * RCHUNK;

  #pragma unroll
  for (int t = 0; t < RCHUNK; ++t) {
    const float m = mp[t];
    msum += m;
    f32x4 r  = *(const f32x4*)(zrp + (size_t)t * DD);
    f32x4 im = *(const f32x4*)(zip + (size_t)t * DD);
    accR += r * m;
    accI += im * m;
  }

  const size_t po = ((size_t)(gb * NCH + c)) * DD + d4;
  *(f32x4*)(partR + po) = accR;
  *(f32x4*)(partI + po) = accI;
  if (tid == 0) cntP[gb * NCH + c] = msum;
}

// ---------------- K2: reduce partials + MLP for one group -------------------
// grid: 16 blocks x 256 = 4096 = GROUPB * D. Each block covers one (gb, d-range).
__global__ __launch_bounds__(256) void mlp_kernel(
    const float* __restrict__ partR, const float* __restrict__ partI,
    const float* __restrict__ cntP,
    const float* __restrict__ W1m, const float* __restrict__ b1m,
    const float* __restrict__ W2m, const float* __restrict__ b2m,
    const float* __restrict__ W1p, const float* __restrict__ b1p,
    const float* __restrict__ W2p, const float* __restrict__ b2p,
    const float* __restrict__ mag_scale,
    float* __restrict__ anR, float* __restrict__ anI) {
  const int gid = blockIdx.x * blockDim.x + threadIdx.x;  // 0..4095
  const int gb = gid >> 10;          // batch within group (whole block same gb)
  const int d = gid & (DD - 1);

  // parallel count reduce (256 chunk counts for this gb)
  __shared__ float red[256];
  red[threadIdx.x] = cntP[gb * NCH + threadIdx.x];
  __syncthreads();
  for (int s = 128; s > 0; s >>= 1) {
    if (threadIdx.x < s) red[threadIdx.x] += red[threadIdx.x + s];
    __syncthreads();
  }
  const float count = fmaxf(red[0], 1.0f);

  float sR = 0.f, sI = 0.f;
  #pragma unroll 8
  for (int c = 0; c < NCH; ++c) {
    const size_t po = ((size_t)(gb * NCH + c)) * DD + d;
    sR += partR[po];
    sI += partI[po];
  }

  const float Ar = sR / count;
  const float Ai = sI / count;
  const float mag = sqrtf(Ar * Ar + Ai * Ai);
  const float log_mag = logf(mag + kEPS);
  const float inv_me = 1.0f / (mag + kEPS);
  const float pr = Ar * inv_me;
  const float pi = Ai * inv_me;

  float md = b2m[0];
  #pragma unroll
  for (int j = 0; j < HH; ++j) {
    float h = log_mag * W1m[j] + b1m[j];
    h = 0.5f * h * (1.0f + erff(h * 0.70710678118654752440f));
    md += h * W2m[j];
  }
  const float lmo = log_mag + mag_scale[0] * md;

  float pv0 = b2p[0];
  float pv1 = b2p[1];
  #pragma unroll
  for (int j = 0; j < HH; ++j) {
    float hp = pr * W1p[2 * j] + pi * W1p[2 * j + 1] + b1p[j];
    hp = 0.5f * hp * (1.0f + erff(hp * 0.70710678118654752440f));
    pv0 += hp * W2p[j];       // W2p[0][j]
    pv1 += hp * W2p[HH + j];  // W2p[1][j]
  }
  const float nrm = fmaxf(sqrtf(pv0 * pv0 + pv1 * pv1), 1e-12f);
  const float r_out = expf(lmo);
  anR[gid] = r_out * pv0 / nrm;
  anI[gid] = r_out * pv1 / nrm;
}

// ---------------- K3: broadcast add + store for one group -------------------
// Same layout as K1. NORMAL Z loads (expect L3 hits on the group's 128MB that
// K1 just streamed). NT stores (don't evict the group's Z with the out stream).
__global__ __launch_bounds__(256) void add_kernel(
    const float* __restrict__ zr, const float* __restrict__ zi,
    const float* __restrict__ anR, const float* __restrict__ anI,
    float* __restrict__ out, int gbase) {
  const int c = blockIdx.x;
  const int gb = blockIdx.y;
  const int b = gbase + gb;
  const int tid = threadIdx.x;
  const int d4 = tid * 4;

  const int o = gb * DD + d4;
  const f32x4 ar4 = *(const f32x4*)(anR + o);
  const f32x4 ai4 = *(const f32x4*)(anI + o);

  const size_t base = ((size_t)b * TT + (size_t)c * RCHUNK) * DD + d4;
  const float* zrp = zr + base;
  const float* zip = zi + base;
  float* out0 = out + base;
  float* out1 = out + (size_t)BB * TT * DD + base;

  #pragma unroll
  for (int t = 0; t < RCHUNK; ++t) {
    const size_t ro = (size_t)t * DD;
    f32x4 r  = *(const f32x4*)(zrp + ro);
    f32x4 im = *(const f32x4*)(zip + ro);
    r += ar4;
    im += ai4;
    __builtin_nontemporal_store(r, (f32x4*)(out0 + ro));
    __builtin_nontemporal_store(im, (f32x4*)(out1 + ro));
  }
}

extern "C" void kernel_launch(void* const* d_in, const int* in_sizes, int n_in,
                              void* d_out, int out_size, void* d_ws, size_t ws_size,
                              hipStream_t stream) {
  const float* zr = (const float*)d_in[0];
  const float* zi = (const float*)d_in[1];
  const float* mask = (const float*)d_in[2];
  const float* W1m = (const float*)d_in[3];
  const float* b1m = (const float*)d_in[4];
  const float* W2m = (const float*)d_in[5];
  const float* b2m = (const float*)d_in[6];
  const float* W1p = (const float*)d_in[7];
  const float* b1p = (const float*)d_in[8];
  const float* W2p = (const float*)d_in[9];
  const float* b2p = (const float*)d_in[10];
  const float* mag_scale = (const float*)d_in[11];

  float* ws = (float*)d_ws;
  // per-group scratch (reused across groups; kernel ordering serializes)
  float* partR = ws;                           // GROUPB*NCH*DD = 1048576 (4MB)
  float* partI = ws + 1048576;                 // 1048576 (4MB)
  float* cntP  = ws + 2097152;                 // GROUPB*NCH = 1024
  float* anR   = ws + 2098176;                 // GROUPB*DD = 4096
  float* anI   = ws + 2102272;                 // 4096

  dim3 g(NCH, GROUPB);
  for (int grp = 0; grp < NGROUP; ++grp) {
    const int gbase = grp * GROUPB;
    reduce_kernel<<<g, 256, 0, stream>>>(zr, zi, mask, partR, partI, cntP, gbase);
    mlp_kernel<<<GROUPB * DD / 256, 256, 0, stream>>>(
        partR, partI, cntP, W1m, b1m, W2m, b2m, W1p, b1p, W2p, b2p, mag_scale,
        anR, anI);
    add_kernel<<<g, 256, 0, stream>>>(zr, zi, anR, anI, (float*)d_out, gbase);
  }
}

// Round 7
// 329.938 us; speedup vs baseline: 1.2558x; 1.2558x over previous
//
#include <hip/hip_runtime.h>
#include <math.h>

#define BB 16
#define TT 4096
#define DD 1024
#define HH 32
#define TC1 128                 // K1 rows per block
#define NC1 (TT / TC1)          // 32 chunks
#define TC3 64                  // K3 rows per block
#define NC3 (TT / TC3)          // 64 chunks

static constexpr float kEPS = 1e-6f;

typedef float f32x4 __attribute__((ext_vector_type(4)));

// ---------------- K1: masked partial sums over T ----------------
// grid: (NC1, B) = (32,16) = 512 blocks, 256 threads; thread owns 4 consecutive d.
__global__ __launch_bounds__(256) void reduce_kernel(
    const float* __restrict__ zr, const float* __restrict__ zi,
    const float* __restrict__ mask,
    float* __restrict__ partR, float* __restrict__ partI,
    float* __restrict__ cntP) {
  const int c = blockIdx.x;
  const int b = blockIdx.y;
  const int tid = threadIdx.x;
  const int d4 = tid * 4;

  f32x4 accR = (f32x4)(0.f);
  f32x4 accI = (f32x4)(0.f);
  float msum = 0.f;

  const size_t base = ((size_t)b * TT + (size_t)c * TC1) * DD + d4;
  const float* zrp = zr + base;
  const float* zip = zi + base;
  const float* mp = mask + (size_t)b * TT + (size_t)c * TC1;

  #pragma unroll 8
  for (int t = 0; t < TC1; ++t) {
    const float m = mp[t];
    msum += m;
    f32x4 r  = *(const f32x4*)(zrp + (size_t)t * DD);
    f32x4 im = *(const f32x4*)(zip + (size_t)t * DD);
    accR += r * m;
    accI += im * m;
  }

  const size_t po = ((size_t)c * BB + b) * DD + d4;
  *(f32x4*)(partR + po) = accR;
  *(f32x4*)(partI + po) = accI;
  if (tid == 0) cntP[c * BB + b] = msum;
}

// ---------------- K2: reduce 32 partials + per-(b,d) MLP ----------------
// grid: 64 blocks x 256 threads = 16384 = B*D.
__global__ __launch_bounds__(256) void mlp_kernel(
    const float* __restrict__ partR, const float* __restrict__ partI,
    const float* __restrict__ cntP,
    const float* __restrict__ W1m, const float* __restrict__ b1m,
    const float* __restrict__ W2m, const float* __restrict__ b2m,
    const float* __restrict__ W1p, const float* __restrict__ b1p,
    const float* __restrict__ W2p, const float* __restrict__ b2p,
    const float* __restrict__ mag_scale,
    float* __restrict__ anR, float* __restrict__ anI) {
  const int i = blockIdx.x * blockDim.x + threadIdx.x;
  const int b = i >> 10;   // D = 1024
  const int d = i & (DD - 1);

  float count = 0.f;
  #pragma unroll
  for (int c = 0; c < NC1; ++c) count += cntP[c * BB + b];
  count = fmaxf(count, 1.0f);

  float sR = 0.f, sI = 0.f;
  #pragma unroll 8
  for (int c = 0; c < NC1; ++c) {
    const size_t po = ((size_t)c * BB + b) * DD + d;
    sR += partR[po];
    sI += partI[po];
  }

  const float Ar = sR / count;
  const float Ai = sI / count;
  const float mag = sqrtf(Ar * Ar + Ai * Ai);
  const float log_mag = logf(mag + kEPS);
  const float inv_me = 1.0f / (mag + kEPS);
  const float pr = Ar * inv_me;
  const float pi = Ai * inv_me;

  float md = b2m[0];
  #pragma unroll
  for (int j = 0; j < HH; ++j) {
    float h = log_mag * W1m[j] + b1m[j];
    h = 0.5f * h * (1.0f + erff(h * 0.70710678118654752440f));
    md += h * W2m[j];
  }
  const float lmo = log_mag + mag_scale[0] * md;

  float pv0 = b2p[0];
  float pv1 = b2p[1];
  #pragma unroll
  for (int j = 0; j < HH; ++j) {
    float hp = pr * W1p[2 * j] + pi * W1p[2 * j + 1] + b1p[j];
    hp = 0.5f * hp * (1.0f + erff(hp * 0.70710678118654752440f));
    pv0 += hp * W2p[j];       // W2p[0][j]
    pv1 += hp * W2p[HH + j];  // W2p[1][j]
  }
  const float nrm = fmaxf(sqrtf(pv0 * pv0 + pv1 * pv1), 1e-12f);
  const float r_out = expf(lmo);
  anR[i] = r_out * pv0 / nrm;
  anI[i] = r_out * pv1 / nrm;
}

// ---------------- K3: broadcast add + write both planes ----------------
// grid (NC3, B) = (64,16) = 1024 blocks. Plain forward streaming, normal
// loads/stores (matches the 6.8 TB/s fill behavior; nt machinery dropped).
__global__ __launch_bounds__(256) void add_kernel(
    const float* __restrict__ zr, const float* __restrict__ zi,
    const float* __restrict__ anR, const float* __restrict__ anI,
    float* __restrict__ out) {
  const int c = blockIdx.x;
  const int b = blockIdx.y;
  const int tid = threadIdx.x;
  const int d4 = tid * 4;

  const int o = b * DD + d4;
  const f32x4 ar4 = *(const f32x4*)(anR + o);
  const f32x4 ai4 = *(const f32x4*)(anI + o);

  const size_t base = ((size_t)b * TT + (size_t)c * TC3) * DD + d4;
  const float* zrp = zr + base;
  const float* zip = zi + base;
  float* out0 = out + base;
  float* out1 = out + (size_t)BB * TT * DD + base;

  #pragma unroll 8
  for (int t = 0; t < TC3; ++t) {
    const size_t ro = (size_t)t * DD;
    f32x4 r  = *(const f32x4*)(zrp + ro);
    f32x4 im = *(const f32x4*)(zip + ro);
    r += ar4;
    im += ai4;
    *(f32x4*)(out0 + ro) = r;
    *(f32x4*)(out1 + ro) = im;
  }
}

extern "C" void kernel_launch(void* const* d_in, const int* in_sizes, int n_in,
                              void* d_out, int out_size, void* d_ws, size_t ws_size,
                              hipStream_t stream) {
  const float* zr = (const float*)d_in[0];
  const float* zi = (const float*)d_in[1];
  const float* mask = (const float*)d_in[2];
  const float* W1m = (const float*)d_in[3];
  const float* b1m = (const float*)d_in[4];
  const float* W2m = (const float*)d_in[5];
  const float* b2m = (const float*)d_in[6];
  const float* W1p = (const float*)d_in[7];
  const float* b1p = (const float*)d_in[8];
  const float* W2p = (const float*)d_in[9];
  const float* b2p = (const float*)d_in[10];
  const float* mag_scale = (const float*)d_in[11];

  float* ws = (float*)d_ws;
  float* partR = ws;                       // NC1*BB*DD = 524288 (2MB)
  float* partI = ws + 524288;              // 524288
  float* cntP  = ws + 1048576;             // NC1*BB = 512
  float* anR   = ws + 1049088;             // 16384
  float* anI   = ws + 1065472;             // 16384

  dim3 g1(NC1, BB);
  reduce_kernel<<<g1, 256, 0, stream>>>(zr, zi, mask, partR, partI, cntP);

  mlp_kernel<<<BB * DD / 256, 256, 0, stream>>>(
      partR, partI, cntP, W1m, b1m, W2m, b2m, W1p, b1p, W2p, b2p, mag_scale,
      anR, anI);

  dim3 g3(NC3, BB);
  add_kernel<<<g3, 256, 0, stream>>>(zr, zi, anR, anI, (float*)d_out);
}

// Round 8
// 301.108 us; speedup vs baseline: 1.3761x; 1.0957x over previous
//
#include <hip/hip_runtime.h>
#include <math.h>

#define BB 16
#define TT 4096
#define DD 1024
#define HH 32
#define TCHUNK 64
#define NCHUNK (TT / TCHUNK)   // 64

static constexpr float kEPS = 1e-6f;

typedef float f32x4 __attribute__((ext_vector_type(4)));

// ---------------- Kernel 1: masked partial sums over T ----------------
// grid: (NCHUNK, B), 256 threads; thread owns 4 consecutive d (256*4 = D).
// NT loads: nothing re-reads Z from cache (no retention across kernels) --
// avoid allocating 512MB of dead lines (same churn fix that won in K3).
__global__ __launch_bounds__(256) void reduce_kernel(
    const float* __restrict__ zr, const float* __restrict__ zi,
    const float* __restrict__ mask,
    float* __restrict__ partR, float* __restrict__ partI,
    float* __restrict__ cntP) {
  const int c = blockIdx.x;
  const int b = blockIdx.y;
  const int tid = threadIdx.x;
  const int d4 = tid * 4;

  f32x4 accR = (f32x4)(0.f);
  f32x4 accI = (f32x4)(0.f);
  float msum = 0.f;

  const size_t base = ((size_t)b * TT + (size_t)c * TCHUNK) * DD + d4;
  const float* zrp = zr + base;
  const float* zip = zi + base;
  const float* mp = mask + (size_t)b * TT + (size_t)c * TCHUNK;

  #pragma unroll 8
  for (int t = 0; t < TCHUNK; ++t) {
    const float m = mp[t];
    msum += m;
    f32x4 r  = __builtin_nontemporal_load((const f32x4*)(zrp + (size_t)t * DD));
    f32x4 im = __builtin_nontemporal_load((const f32x4*)(zip + (size_t)t * DD));
    accR += r * m;
    accI += im * m;
  }

  const size_t po = ((size_t)c * BB + b) * DD + d4;
  *(f32x4*)(partR + po) = accR;
  *(f32x4*)(partI + po) = accI;
  if (tid == 0) cntP[c * BB + b] = msum;
}

// ---------------- Kernel 2: reduce partials + per-(b,d) MLP ----------------
// grid: 256 blocks x 64 threads = 16384 = B*D (one wave per block; 4x more
// blocks than before to spread the latency-bound strided reduce across CUs).
__global__ __launch_bounds__(64) void mlp_kernel(
    const float* __restrict__ partR, const float* __restrict__ partI,
    const float* __restrict__ cntP,
    const float* __restrict__ W1m, const float* __restrict__ b1m,
    const float* __restrict__ W2m, const float* __restrict__ b2m,
    const float* __restrict__ W1p, const float* __restrict__ b1p,
    const float* __restrict__ W2p, const float* __restrict__ b2p,
    const float* __restrict__ mag_scale,
    float* __restrict__ anR, float* __restrict__ anI) {
  const int i = blockIdx.x * blockDim.x + threadIdx.x;
  const int b = i >> 10;   // D = 1024
  const int d = i & (DD - 1);

  float count = 0.f;
  #pragma unroll 8
  for (int c = 0; c < NCHUNK; ++c) count += cntP[c * BB + b];
  count = fmaxf(count, 1.0f);

  float sR = 0.f, sI = 0.f;
  #pragma unroll 8
  for (int c = 0; c < NCHUNK; ++c) {
    const size_t po = ((size_t)c * BB + b) * DD + d;
    sR += partR[po];
    sI += partI[po];
  }

  const float Ar = sR / count;
  const float Ai = sI / count;
  const float mag = sqrtf(Ar * Ar + Ai * Ai);
  const float log_mag = logf(mag + kEPS);
  const float inv_me = 1.0f / (mag + kEPS);
  const float pr = Ar * inv_me;
  const float pi = Ai * inv_me;

  float md = b2m[0];
  #pragma unroll
  for (int j = 0; j < HH; ++j) {
    float h = log_mag * W1m[j] + b1m[j];
    h = 0.5f * h * (1.0f + erff(h * 0.70710678118654752440f));
    md += h * W2m[j];
  }
  const float lmo = log_mag + mag_scale[0] * md;

  float pv0 = b2p[0];
  float pv1 = b2p[1];
  #pragma unroll
  for (int j = 0; j < HH; ++j) {
    float hp = pr * W1p[2 * j] + pi * W1p[2 * j + 1] + b1p[j];
    hp = 0.5f * hp * (1.0f + erff(hp * 0.70710678118654752440f));
    pv0 += hp * W2p[j];       // W2p[0][j]
    pv1 += hp * W2p[HH + j];  // W2p[1][j]
  }
  const float nrm = fmaxf(sqrtf(pv0 * pv0 + pv1 * pv1), 1e-12f);
  const float r_out = expf(lmo);
  anR[i] = r_out * pv0 / nrm;
  anI[i] = r_out * pv1 / nrm;
}

// ---------------- Kernel 3: broadcast add + write both planes ----------------
// R4's best-measured version: backward t-walk, NT loads (no dead allocation),
// NT stores (no write-allocate churn).
__global__ __launch_bounds__(256) void add_kernel(
    const float* __restrict__ zr, const float* __restrict__ zi,
    const float* __restrict__ anR, const float* __restrict__ anI,
    float* __restrict__ out) {
  const int c = blockIdx.x;
  const int b = blockIdx.y;
  const int tid = threadIdx.x;
  const int d4 = tid * 4;

  const int o = b * DD + d4;
  const f32x4 ar4 = *(const f32x4*)(anR + o);
  const f32x4 ai4 = *(const f32x4*)(anI + o);

  const size_t base = ((size_t)b * TT + (size_t)c * TCHUNK) * DD + d4;
  const float* zrp = zr + base;
  const float* zip = zi + base;
  float* out0 = out + base;
  float* out1 = out + (size_t)BB * TT * DD + base;

  #pragma unroll 8
  for (int t = TCHUNK - 1; t >= 0; --t) {
    const size_t ro = (size_t)t * DD;
    f32x4 r  = __builtin_nontemporal_load((const f32x4*)(zrp + ro));
    f32x4 im = __builtin_nontemporal_load((const f32x4*)(zip + ro));
    r += ar4;
    im += ai4;
    __builtin_nontemporal_store(r, (f32x4*)(out0 + ro));
    __builtin_nontemporal_store(im, (f32x4*)(out1 + ro));
  }
}

extern "C" void kernel_launch(void* const* d_in, const int* in_sizes, int n_in,
                              void* d_out, int out_size, void* d_ws, size_t ws_size,
                              hipStream_t stream) {
  const float* zr = (const float*)d_in[0];
  const float* zi = (const float*)d_in[1];
  const float* mask = (const float*)d_in[2];
  const float* W1m = (const float*)d_in[3];
  const float* b1m = (const float*)d_in[4];
  const float* W2m = (const float*)d_in[5];
  const float* b2m = (const float*)d_in[6];
  const float* W1p = (const float*)d_in[7];
  const float* b1p = (const float*)d_in[8];
  const float* W2p = (const float*)d_in[9];
  const float* b2p = (const float*)d_in[10];
  const float* mag_scale = (const float*)d_in[11];

  float* ws = (float*)d_ws;
  float* partR = ws;                       // NCHUNK*B*D = 1048576
  float* partI = ws + 1048576;             // 1048576
  float* cntP  = ws + 2097152;             // NCHUNK*B = 1024
  float* anR   = ws + 2098176;             // 16384
  float* anI   = ws + 2114560;             // 16384

  dim3 g(NCHUNK, BB);
  reduce_kernel<<<g, 256, 0, stream>>>(zr, zi, mask, partR, partI, cntP);

  mlp_kernel<<<BB * DD / 64, 64, 0, stream>>>(
      partR, partI, cntP, W1m, b1m, W2m, b2m, W1p, b1p, W2p, b2p, mag_scale,
      anR, anI);

  add_kernel<<<g, 256, 0, stream>>>(zr, zi, anR, anI, (float*)d_out);
}